// Round 1
// baseline (2174.578 us; speedup 1.0000x reference)
//
#include <hip/hip_runtime.h>
#include <math.h>

#define NH   4096
#define KCAT 8192
#define TPTS 16

// ---------------------------------------------------------------------------
// Wave (64-lane) sum reduction
// ---------------------------------------------------------------------------
__device__ __forceinline__ float wave_reduce64(float s) {
#pragma unroll
    for (int off = 32; off > 0; off >>= 1)
        s += __shfl_down(s, off, 64);
    return s;
}

// ---------------------------------------------------------------------------
// H[0][i] = h_f[i]; H[1][i] = h_b[i]
// ---------------------------------------------------------------------------
__global__ __launch_bounds__(256) void init_h_kernel(const float* __restrict__ h_f,
                                                     const float* __restrict__ h_b,
                                                     float* __restrict__ H) {
    int i = blockIdx.x * 256 + threadIdx.x;
    H[i]      = h_f[i];
    H[NH + i] = h_b[i];
}

// ---------------------------------------------------------------------------
// RK4 stage, first matvec:
//   V[c][row] = tanh( dot(W1[row,:], H[c] + alpha_c * K[c]) + b1[row] )
// alpha_c = coef * dt_c, dt_c read from t arrays. useK==0 -> alpha = 0, K unread.
// Wave-per-row: 4 waves/block, grid = NH/4 blocks.
// ---------------------------------------------------------------------------
__global__ __launch_bounds__(256) void rk4_mv1(
    const float* __restrict__ W1, const float* __restrict__ b1,
    const float* __restrict__ H,  const float* __restrict__ Kv,
    const float* __restrict__ tf, const float* __restrict__ tb,
    int tidx, float coef, int useK,
    float* __restrict__ V)
{
    const int row  = blockIdx.x * 4 + (threadIdx.x >> 6);
    const int lane = threadIdx.x & 63;
    const float dt0 = tf[tidx + 1] - tf[tidx];
    const float dt1 = tb[tidx + 1] - tb[tidx];
    const float a0 = coef * dt0;
    const float a1 = coef * dt1;

    const float4* __restrict__ W4 = (const float4*)(W1 + (size_t)row * NH);
    const float4* __restrict__ x0 = (const float4*)(H);
    const float4* __restrict__ x1 = (const float4*)(H + NH);
    const float4* __restrict__ k0 = (const float4*)(Kv);
    const float4* __restrict__ k1 = (const float4*)(Kv + NH);

    float s0 = 0.f, s1 = 0.f;
    if (useK) {
#pragma unroll 8
        for (int i = 0; i < NH / 4 / 64; ++i) {
            int idx = lane + i * 64;
            float4 w  = W4[idx];
            float4 h0 = x0[idx], h1 = x1[idx];
            float4 p0 = k0[idx], p1 = k1[idx];
            s0 += w.x * (h0.x + a0 * p0.x) + w.y * (h0.y + a0 * p0.y)
                + w.z * (h0.z + a0 * p0.z) + w.w * (h0.w + a0 * p0.w);
            s1 += w.x * (h1.x + a1 * p1.x) + w.y * (h1.y + a1 * p1.y)
                + w.z * (h1.z + a1 * p1.z) + w.w * (h1.w + a1 * p1.w);
        }
    } else {
#pragma unroll 8
        for (int i = 0; i < NH / 4 / 64; ++i) {
            int idx = lane + i * 64;
            float4 w  = W4[idx];
            float4 h0 = x0[idx], h1 = x1[idx];
            s0 += w.x * h0.x + w.y * h0.y + w.z * h0.z + w.w * h0.w;
            s1 += w.x * h1.x + w.y * h1.y + w.z * h1.z + w.w * h1.w;
        }
    }
    s0 = wave_reduce64(s0);
    s1 = wave_reduce64(s1);
    if (lane == 0) {
        float bb = b1[row];
        V[row]      = tanhf(s0 + bb);
        V[NH + row] = tanhf(s1 + bb);
    }
}

// ---------------------------------------------------------------------------
// RK4 stage, second matvec + accumulator update:
//   K[c][row]   = dot(W2[row,:], V[c]) + b2[row]
//   ACC[c][row] = Hbase[c][row] + wgt * (dt_c/6) * K[c][row]
// Stage 1: Hbase = H (fresh), wgt=1. Stages 2,3: Hbase = ACC (in-place), wgt=2.
// Stage 4: Hbase = ACC, wgt=1.
// ---------------------------------------------------------------------------
__global__ __launch_bounds__(256) void rk4_mv2(
    const float* __restrict__ W2, const float* __restrict__ b2,
    const float* __restrict__ V,
    const float* __restrict__ tf, const float* __restrict__ tb,
    int tidx, float wgt,
    const float* __restrict__ Hbase,
    float* __restrict__ Kout, float* __restrict__ ACC)
{
    const int row  = blockIdx.x * 4 + (threadIdx.x >> 6);
    const int lane = threadIdx.x & 63;

    const float4* __restrict__ W4 = (const float4*)(W2 + (size_t)row * NH);
    const float4* __restrict__ v0 = (const float4*)(V);
    const float4* __restrict__ v1 = (const float4*)(V + NH);

    float s0 = 0.f, s1 = 0.f;
#pragma unroll 8
    for (int i = 0; i < NH / 4 / 64; ++i) {
        int idx = lane + i * 64;
        float4 w  = W4[idx];
        float4 a  = v0[idx], b = v1[idx];
        s0 += w.x * a.x + w.y * a.y + w.z * a.z + w.w * a.w;
        s1 += w.x * b.x + w.y * b.y + w.z * b.z + w.w * b.w;
    }
    s0 = wave_reduce64(s0);
    s1 = wave_reduce64(s1);
    if (lane == 0) {
        float bb  = b2[row];
        float k0v = s0 + bb;
        float k1v = s1 + bb;
        Kout[row]      = k0v;
        Kout[NH + row] = k1v;
        const float dt0 = tf[tidx + 1] - tf[tidx];
        const float dt1 = tb[tidx + 1] - tb[tidx];
        ACC[row]      = Hbase[row]      + wgt * (dt0 / 6.f) * k0v;
        ACC[NH + row] = Hbase[NH + row] + wgt * (dt1 / 6.f) * k1v;
    }
}

// ---------------------------------------------------------------------------
// Build GRU concat inputs:
//   xcat1[c] = [x_c, h_c] ; xcat2[c] = [x_c, <filled by gru_mv1>]
// ---------------------------------------------------------------------------
__global__ __launch_bounds__(256) void build_xcat_kernel(
    const float* __restrict__ x_f, const float* __restrict__ x_b,
    const float* __restrict__ H,
    float* __restrict__ xcat1, float* __restrict__ xcat2)
{
    int i = blockIdx.x * 256 + threadIdx.x;
    float xf = x_f[i], xb = x_b[i];
    xcat1[i]               = xf;
    xcat2[i]               = xf;
    xcat1[KCAT + i]        = xb;
    xcat2[KCAT + i]        = xb;
    xcat1[NH + i]          = H[i];
    xcat1[KCAT + NH + i]   = H[NH + i];
}

// ---------------------------------------------------------------------------
// GRU gate matvec (K = 8192):
//   G[c][row] = sigmoid( dot(Wi[row,:], xcat1[c]) + bi[row] )
//   xcat2[c][NH + row] = G[c][row] * H[c][row]
// ---------------------------------------------------------------------------
__global__ __launch_bounds__(256) void gru_mv1(
    const float* __restrict__ Wi, const float* __restrict__ bi,
    const float* __restrict__ xcat1, const float* __restrict__ H,
    float* __restrict__ G, float* __restrict__ xcat2)
{
    const int row  = blockIdx.x * 4 + (threadIdx.x >> 6);
    const int lane = threadIdx.x & 63;

    const float4* __restrict__ W4 = (const float4*)(Wi + (size_t)row * KCAT);
    const float4* __restrict__ c0 = (const float4*)(xcat1);
    const float4* __restrict__ c1 = (const float4*)(xcat1 + KCAT);

    float s0 = 0.f, s1 = 0.f;
#pragma unroll 8
    for (int i = 0; i < KCAT / 4 / 64; ++i) {
        int idx = lane + i * 64;
        float4 w = W4[idx];
        float4 a = c0[idx], b = c1[idx];
        s0 += w.x * a.x + w.y * a.y + w.z * a.z + w.w * a.w;
        s1 += w.x * b.x + w.y * b.y + w.z * b.z + w.w * b.w;
    }
    s0 = wave_reduce64(s0);
    s1 = wave_reduce64(s1);
    if (lane == 0) {
        float bb = bi[row];
        float g0 = 1.f / (1.f + expf(-(s0 + bb)));
        float g1 = 1.f / (1.f + expf(-(s1 + bb)));
        G[row]      = g0;
        G[NH + row] = g1;
        xcat2[NH + row]        = g0 * H[row];
        xcat2[KCAT + NH + row] = g1 * H[NH + row];
    }
}

// ---------------------------------------------------------------------------
// GRU candidate matvec + blend (K = 8192):
//   hh = tanh( dot(Wi[row,:], xcat2[c]) + bi[row] )
//   hnew = g*h + (1-g)*hh ;  writes d_out[NH..3NH) and hcat for the head.
// ---------------------------------------------------------------------------
__global__ __launch_bounds__(256) void gru_mv2(
    const float* __restrict__ Wi, const float* __restrict__ bi,
    const float* __restrict__ xcat2, const float* __restrict__ H,
    const float* __restrict__ G,
    float* __restrict__ out, float* __restrict__ hcat)
{
    const int row  = blockIdx.x * 4 + (threadIdx.x >> 6);
    const int lane = threadIdx.x & 63;

    const float4* __restrict__ W4 = (const float4*)(Wi + (size_t)row * KCAT);
    const float4* __restrict__ c0 = (const float4*)(xcat2);
    const float4* __restrict__ c1 = (const float4*)(xcat2 + KCAT);

    float s0 = 0.f, s1 = 0.f;
#pragma unroll 8
    for (int i = 0; i < KCAT / 4 / 64; ++i) {
        int idx = lane + i * 64;
        float4 w = W4[idx];
        float4 a = c0[idx], b = c1[idx];
        s0 += w.x * a.x + w.y * a.y + w.z * a.z + w.w * a.w;
        s1 += w.x * b.x + w.y * b.y + w.z * b.z + w.w * b.w;
    }
    s0 = wave_reduce64(s0);
    s1 = wave_reduce64(s1);
    if (lane == 0) {
        float bb  = bi[row];
        float hh0 = tanhf(s0 + bb);
        float hh1 = tanhf(s1 + bb);
        float g0  = G[row], g1 = G[NH + row];
        float hf  = g0 * H[row]      + (1.f - g0) * hh0;
        float hb  = g1 * H[NH + row] + (1.f - g1) * hh1;
        out[NH + row]     = hf;   // output tuple slot 1: h_f
        out[2 * NH + row] = hb;   // output tuple slot 2: h_b
        hcat[row]      = hf;
        hcat[NH + row] = hb;
    }
}

// ---------------------------------------------------------------------------
// Output head (single column, K = 8192):
//   out[row] = dot(h2o_W[row,:], hcat) + h2o_b[row]
// ---------------------------------------------------------------------------
__global__ __launch_bounds__(256) void h2o_mv(
    const float* __restrict__ W, const float* __restrict__ b,
    const float* __restrict__ hcat, float* __restrict__ out)
{
    const int row  = blockIdx.x * 4 + (threadIdx.x >> 6);
    const int lane = threadIdx.x & 63;

    const float4* __restrict__ W4 = (const float4*)(W + (size_t)row * KCAT);
    const float4* __restrict__ x4 = (const float4*)(hcat);

    float s = 0.f;
#pragma unroll 8
    for (int i = 0; i < KCAT / 4 / 64; ++i) {
        int idx = lane + i * 64;
        float4 w = W4[idx];
        float4 a = x4[idx];
        s += w.x * a.x + w.y * a.y + w.z * a.z + w.w * a.w;
    }
    s = wave_reduce64(s);
    if (lane == 0)
        out[row] = s + b[row];
}

// ---------------------------------------------------------------------------
extern "C" void kernel_launch(void* const* d_in, const int* in_sizes, int n_in,
                              void* d_out, int out_size, void* d_ws, size_t ws_size,
                              hipStream_t stream) {
    const float* x_f   = (const float*)d_in[0];
    const float* x_b   = (const float*)d_in[1];
    const float* h_f   = (const float*)d_in[2];
    const float* h_b   = (const float*)d_in[3];
    const float* t_f   = (const float*)d_in[4];
    const float* t_b   = (const float*)d_in[5];
    const float* i2h_W = (const float*)d_in[6];
    const float* i2h_b = (const float*)d_in[7];
    const float* h2o_W = (const float*)d_in[8];
    const float* h2o_b = (const float*)d_in[9];
    const float* f_W1  = (const float*)d_in[10];
    const float* f_b1  = (const float*)d_in[11];
    const float* f_W2  = (const float*)d_in[12];
    const float* f_b2  = (const float*)d_in[13];
    float* out = (float*)d_out;

    float* ws    = (float*)d_ws;
    float* bufA  = ws;                  // 2*NH
    float* bufB  = bufA  + 2 * NH;      // 2*NH
    float* V     = bufB  + 2 * NH;      // 2*NH
    float* Kv    = V     + 2 * NH;      // 2*NH
    float* xcat1 = Kv    + 2 * NH;      // 2*KCAT
    float* xcat2 = xcat1 + 2 * KCAT;    // 2*KCAT
    float* G     = xcat2 + 2 * KCAT;    // 2*NH
    float* hcat  = G     + 2 * NH;      // KCAT

    dim3 blk(256);
    const int mv_grid = NH / 4;   // wave-per-row, 4 waves per block

    init_h_kernel<<<NH / 256, blk, 0, stream>>>(h_f, h_b, bufA);

    float* H   = bufA;
    float* ACC = bufB;
    for (int s = 0; s < TPTS - 1; ++s) {
        // stage 1: k1 = f(h)
        rk4_mv1<<<mv_grid, blk, 0, stream>>>(f_W1, f_b1, H, Kv, t_f, t_b, s, 0.0f, 0, V);
        rk4_mv2<<<mv_grid, blk, 0, stream>>>(f_W2, f_b2, V, t_f, t_b, s, 1.0f, H,   Kv, ACC);
        // stage 2: k2 = f(h + dt/2 * k1)
        rk4_mv1<<<mv_grid, blk, 0, stream>>>(f_W1, f_b1, H, Kv, t_f, t_b, s, 0.5f, 1, V);
        rk4_mv2<<<mv_grid, blk, 0, stream>>>(f_W2, f_b2, V, t_f, t_b, s, 2.0f, ACC, Kv, ACC);
        // stage 3: k3 = f(h + dt/2 * k2)
        rk4_mv1<<<mv_grid, blk, 0, stream>>>(f_W1, f_b1, H, Kv, t_f, t_b, s, 0.5f, 1, V);
        rk4_mv2<<<mv_grid, blk, 0, stream>>>(f_W2, f_b2, V, t_f, t_b, s, 2.0f, ACC, Kv, ACC);
        // stage 4: k4 = f(h + dt * k3)
        rk4_mv1<<<mv_grid, blk, 0, stream>>>(f_W1, f_b1, H, Kv, t_f, t_b, s, 1.0f, 1, V);
        rk4_mv2<<<mv_grid, blk, 0, stream>>>(f_W2, f_b2, V, t_f, t_b, s, 1.0f, ACC, Kv, ACC);
        // h <- h + dt/6 (k1 + 2k2 + 2k3 + k4)
        float* tmp = H; H = ACC; ACC = tmp;
    }

    build_xcat_kernel<<<NH / 256, blk, 0, stream>>>(x_f, x_b, H, xcat1, xcat2);
    gru_mv1<<<mv_grid, blk, 0, stream>>>(i2h_W, i2h_b, xcat1, H, G, xcat2);
    gru_mv2<<<mv_grid, blk, 0, stream>>>(i2h_W, i2h_b, xcat2, H, G, out, hcat);
    h2o_mv <<<mv_grid, blk, 0, stream>>>(h2o_W, h2o_b, hcat, out);
}

// Round 2
// 1572.509 us; speedup vs baseline: 1.3829x; 1.3829x over previous
//
#include <hip/hip_runtime.h>
#include <math.h>

#define NH   4096
#define KCAT 8192
#define TPTS 16

typedef unsigned short ushort_t;

// ---------------------------------------------------------------------------
// Wave (64-lane) sum reduction
// ---------------------------------------------------------------------------
__device__ __forceinline__ float wave_reduce64(float s) {
#pragma unroll
    for (int off = 32; off > 0; off >>= 1)
        s += __shfl_down(s, off, 64);
    return s;
}

// ---------------------------------------------------------------------------
// fp32 -> bf16 (RNE, finite inputs) and bf16x8 unpack
// ---------------------------------------------------------------------------
__device__ __forceinline__ unsigned f2bf_pack2(float lo, float hi) {
    unsigned ul = __float_as_uint(lo);
    unsigned uh = __float_as_uint(hi);
    ul = (ul + 0x7fffu + ((ul >> 16) & 1u)) >> 16;
    uh = (uh + 0x7fffu + ((uh >> 16) & 1u)) >> 16;
    return ul | (uh << 16);
}

__device__ __forceinline__ void bf16x8_to_f32(uint4 w, float* f) {
    f[0] = __uint_as_float(w.x << 16); f[1] = __uint_as_float(w.x & 0xffff0000u);
    f[2] = __uint_as_float(w.y << 16); f[3] = __uint_as_float(w.y & 0xffff0000u);
    f[4] = __uint_as_float(w.z << 16); f[5] = __uint_as_float(w.z & 0xffff0000u);
    f[6] = __uint_as_float(w.w << 16); f[7] = __uint_as_float(w.w & 0xffff0000u);
}

// Each thread converts 8 floats -> 8 bf16 (16B read x2, 16B write)
__global__ __launch_bounds__(256) void cvt_bf16_kernel(const float* __restrict__ src,
                                                       ushort_t* __restrict__ dst, int n8) {
    int i = blockIdx.x * 256 + threadIdx.x;
    if (i < n8) {
        const float4* s4 = (const float4*)src;
        float4 a = s4[2 * i], b = s4[2 * i + 1];
        uint4 o;
        o.x = f2bf_pack2(a.x, a.y);
        o.y = f2bf_pack2(a.z, a.w);
        o.z = f2bf_pack2(b.x, b.y);
        o.w = f2bf_pack2(b.z, b.w);
        ((uint4*)dst)[i] = o;
    }
}

// ---------------------------------------------------------------------------
// H[0][i] = h_f[i]; H[1][i] = h_b[i]
// ---------------------------------------------------------------------------
__global__ __launch_bounds__(256) void init_h_kernel(const float* __restrict__ h_f,
                                                     const float* __restrict__ h_b,
                                                     float* __restrict__ H) {
    int i = blockIdx.x * 256 + threadIdx.x;
    H[i]      = h_f[i];
    H[NH + i] = h_b[i];
}

// ===========================================================================
// BF16-weight RK4 matvecs (weights bf16, activations/accum fp32)
// ===========================================================================

// V[c][row] = tanh( dot(W1[row,:], H[c] + alpha_c*K[c]) + b1[row] )
__global__ __launch_bounds__(256) void rk4_mv1_bf16(
    const ushort_t* __restrict__ W1, const float* __restrict__ b1,
    const float* __restrict__ H,  const float* __restrict__ Kv,
    const float* __restrict__ tf, const float* __restrict__ tb,
    int tidx, float coef, int useK,
    float* __restrict__ V)
{
    const int row  = blockIdx.x * 4 + (threadIdx.x >> 6);
    const int lane = threadIdx.x & 63;
    const float a0 = coef * (tf[tidx + 1] - tf[tidx]);
    const float a1 = coef * (tb[tidx + 1] - tb[tidx]);

    const uint4*  __restrict__ W4 = (const uint4*)(W1 + (size_t)row * NH);
    const float4* __restrict__ x0 = (const float4*)(H);
    const float4* __restrict__ x1 = (const float4*)(H + NH);
    const float4* __restrict__ k0 = (const float4*)(Kv);
    const float4* __restrict__ k1 = (const float4*)(Kv + NH);

    float s0 = 0.f, s1 = 0.f;
    if (useK) {
#pragma unroll
        for (int i = 0; i < NH / 8 / 64; ++i) {
            int idx = lane + i * 64;
            uint4 w = W4[idx];
            float wf[8], h0[8], h1[8], p0[8], p1[8];
            bf16x8_to_f32(w, wf);
            *(float4*)&h0[0] = x0[2 * idx]; *(float4*)&h0[4] = x0[2 * idx + 1];
            *(float4*)&h1[0] = x1[2 * idx]; *(float4*)&h1[4] = x1[2 * idx + 1];
            *(float4*)&p0[0] = k0[2 * idx]; *(float4*)&p0[4] = k0[2 * idx + 1];
            *(float4*)&p1[0] = k1[2 * idx]; *(float4*)&p1[4] = k1[2 * idx + 1];
#pragma unroll
            for (int j = 0; j < 8; ++j) {
                s0 += wf[j] * (h0[j] + a0 * p0[j]);
                s1 += wf[j] * (h1[j] + a1 * p1[j]);
            }
        }
    } else {
#pragma unroll
        for (int i = 0; i < NH / 8 / 64; ++i) {
            int idx = lane + i * 64;
            uint4 w = W4[idx];
            float wf[8], h0[8], h1[8];
            bf16x8_to_f32(w, wf);
            *(float4*)&h0[0] = x0[2 * idx]; *(float4*)&h0[4] = x0[2 * idx + 1];
            *(float4*)&h1[0] = x1[2 * idx]; *(float4*)&h1[4] = x1[2 * idx + 1];
#pragma unroll
            for (int j = 0; j < 8; ++j) {
                s0 += wf[j] * h0[j];
                s1 += wf[j] * h1[j];
            }
        }
    }
    s0 = wave_reduce64(s0);
    s1 = wave_reduce64(s1);
    if (lane == 0) {
        float bb = b1[row];
        V[row]      = tanhf(s0 + bb);
        V[NH + row] = tanhf(s1 + bb);
    }
}

// K[c][row] = dot(W2[row,:], V[c]) + b2[row];  ACC = Hbase + wgt*(dt/6)*K
__global__ __launch_bounds__(256) void rk4_mv2_bf16(
    const ushort_t* __restrict__ W2, const float* __restrict__ b2,
    const float* __restrict__ V,
    const float* __restrict__ tf, const float* __restrict__ tb,
    int tidx, float wgt,
    const float* __restrict__ Hbase,
    float* __restrict__ Kout, float* __restrict__ ACC)
{
    const int row  = blockIdx.x * 4 + (threadIdx.x >> 6);
    const int lane = threadIdx.x & 63;

    const uint4*  __restrict__ W4 = (const uint4*)(W2 + (size_t)row * NH);
    const float4* __restrict__ v0 = (const float4*)(V);
    const float4* __restrict__ v1 = (const float4*)(V + NH);

    float s0 = 0.f, s1 = 0.f;
#pragma unroll
    for (int i = 0; i < NH / 8 / 64; ++i) {
        int idx = lane + i * 64;
        uint4 w = W4[idx];
        float wf[8], a[8], b[8];
        bf16x8_to_f32(w, wf);
        *(float4*)&a[0] = v0[2 * idx]; *(float4*)&a[4] = v0[2 * idx + 1];
        *(float4*)&b[0] = v1[2 * idx]; *(float4*)&b[4] = v1[2 * idx + 1];
#pragma unroll
        for (int j = 0; j < 8; ++j) {
            s0 += wf[j] * a[j];
            s1 += wf[j] * b[j];
        }
    }
    s0 = wave_reduce64(s0);
    s1 = wave_reduce64(s1);
    if (lane == 0) {
        float bb  = b2[row];
        float k0v = s0 + bb;
        float k1v = s1 + bb;
        Kout[row]      = k0v;
        Kout[NH + row] = k1v;
        const float dt0 = tf[tidx + 1] - tf[tidx];
        const float dt1 = tb[tidx + 1] - tb[tidx];
        ACC[row]      = Hbase[row]      + wgt * (dt0 / 6.f) * k0v;
        ACC[NH + row] = Hbase[NH + row] + wgt * (dt1 / 6.f) * k1v;
    }
}

// ===========================================================================
// FP32-weight fallback RK4 matvecs (used only if ws too small for bf16)
// ===========================================================================
__global__ __launch_bounds__(256) void rk4_mv1_f32(
    const float* __restrict__ W1, const float* __restrict__ b1,
    const float* __restrict__ H,  const float* __restrict__ Kv,
    const float* __restrict__ tf, const float* __restrict__ tb,
    int tidx, float coef, int useK,
    float* __restrict__ V)
{
    const int row  = blockIdx.x * 4 + (threadIdx.x >> 6);
    const int lane = threadIdx.x & 63;
    const float a0 = coef * (tf[tidx + 1] - tf[tidx]);
    const float a1 = coef * (tb[tidx + 1] - tb[tidx]);

    const float4* __restrict__ W4 = (const float4*)(W1 + (size_t)row * NH);
    const float4* __restrict__ x0 = (const float4*)(H);
    const float4* __restrict__ x1 = (const float4*)(H + NH);
    const float4* __restrict__ k0 = (const float4*)(Kv);
    const float4* __restrict__ k1 = (const float4*)(Kv + NH);

    float s0 = 0.f, s1 = 0.f;
    if (useK) {
#pragma unroll 8
        for (int i = 0; i < NH / 4 / 64; ++i) {
            int idx = lane + i * 64;
            float4 w  = W4[idx];
            float4 h0 = x0[idx], h1 = x1[idx];
            float4 p0 = k0[idx], p1 = k1[idx];
            s0 += w.x * (h0.x + a0 * p0.x) + w.y * (h0.y + a0 * p0.y)
                + w.z * (h0.z + a0 * p0.z) + w.w * (h0.w + a0 * p0.w);
            s1 += w.x * (h1.x + a1 * p1.x) + w.y * (h1.y + a1 * p1.y)
                + w.z * (h1.z + a1 * p1.z) + w.w * (h1.w + a1 * p1.w);
        }
    } else {
#pragma unroll 8
        for (int i = 0; i < NH / 4 / 64; ++i) {
            int idx = lane + i * 64;
            float4 w  = W4[idx];
            float4 h0 = x0[idx], h1 = x1[idx];
            s0 += w.x * h0.x + w.y * h0.y + w.z * h0.z + w.w * h0.w;
            s1 += w.x * h1.x + w.y * h1.y + w.z * h1.z + w.w * h1.w;
        }
    }
    s0 = wave_reduce64(s0);
    s1 = wave_reduce64(s1);
    if (lane == 0) {
        float bb = b1[row];
        V[row]      = tanhf(s0 + bb);
        V[NH + row] = tanhf(s1 + bb);
    }
}

__global__ __launch_bounds__(256) void rk4_mv2_f32(
    const float* __restrict__ W2, const float* __restrict__ b2,
    const float* __restrict__ V,
    const float* __restrict__ tf, const float* __restrict__ tb,
    int tidx, float wgt,
    const float* __restrict__ Hbase,
    float* __restrict__ Kout, float* __restrict__ ACC)
{
    const int row  = blockIdx.x * 4 + (threadIdx.x >> 6);
    const int lane = threadIdx.x & 63;

    const float4* __restrict__ W4 = (const float4*)(W2 + (size_t)row * NH);
    const float4* __restrict__ v0 = (const float4*)(V);
    const float4* __restrict__ v1 = (const float4*)(V + NH);

    float s0 = 0.f, s1 = 0.f;
#pragma unroll 8
    for (int i = 0; i < NH / 4 / 64; ++i) {
        int idx = lane + i * 64;
        float4 w = W4[idx];
        float4 a = v0[idx], b = v1[idx];
        s0 += w.x * a.x + w.y * a.y + w.z * a.z + w.w * a.w;
        s1 += w.x * b.x + w.y * b.y + w.z * b.z + w.w * b.w;
    }
    s0 = wave_reduce64(s0);
    s1 = wave_reduce64(s1);
    if (lane == 0) {
        float bb  = b2[row];
        float k0v = s0 + bb;
        float k1v = s1 + bb;
        Kout[row]      = k0v;
        Kout[NH + row] = k1v;
        const float dt0 = tf[tidx + 1] - tf[tidx];
        const float dt1 = tb[tidx + 1] - tb[tidx];
        ACC[row]      = Hbase[row]      + wgt * (dt0 / 6.f) * k0v;
        ACC[NH + row] = Hbase[NH + row] + wgt * (dt1 / 6.f) * k1v;
    }
}

// ---------------------------------------------------------------------------
// GRU / head kernels (fp32 weights; used 1-2x each, conversion doesn't pay)
// ---------------------------------------------------------------------------
__global__ __launch_bounds__(256) void build_xcat_kernel(
    const float* __restrict__ x_f, const float* __restrict__ x_b,
    const float* __restrict__ H,
    float* __restrict__ xcat1, float* __restrict__ xcat2)
{
    int i = blockIdx.x * 256 + threadIdx.x;
    float xf = x_f[i], xb = x_b[i];
    xcat1[i]               = xf;
    xcat2[i]               = xf;
    xcat1[KCAT + i]        = xb;
    xcat2[KCAT + i]        = xb;
    xcat1[NH + i]          = H[i];
    xcat1[KCAT + NH + i]   = H[NH + i];
}

__global__ __launch_bounds__(256) void gru_mv1(
    const float* __restrict__ Wi, const float* __restrict__ bi,
    const float* __restrict__ xcat1, const float* __restrict__ H,
    float* __restrict__ G, float* __restrict__ xcat2)
{
    const int row  = blockIdx.x * 4 + (threadIdx.x >> 6);
    const int lane = threadIdx.x & 63;

    const float4* __restrict__ W4 = (const float4*)(Wi + (size_t)row * KCAT);
    const float4* __restrict__ c0 = (const float4*)(xcat1);
    const float4* __restrict__ c1 = (const float4*)(xcat1 + KCAT);

    float s0 = 0.f, s1 = 0.f;
#pragma unroll 8
    for (int i = 0; i < KCAT / 4 / 64; ++i) {
        int idx = lane + i * 64;
        float4 w = W4[idx];
        float4 a = c0[idx], b = c1[idx];
        s0 += w.x * a.x + w.y * a.y + w.z * a.z + w.w * a.w;
        s1 += w.x * b.x + w.y * b.y + w.z * b.z + w.w * b.w;
    }
    s0 = wave_reduce64(s0);
    s1 = wave_reduce64(s1);
    if (lane == 0) {
        float bb = bi[row];
        float g0 = 1.f / (1.f + expf(-(s0 + bb)));
        float g1 = 1.f / (1.f + expf(-(s1 + bb)));
        G[row]      = g0;
        G[NH + row] = g1;
        xcat2[NH + row]        = g0 * H[row];
        xcat2[KCAT + NH + row] = g1 * H[NH + row];
    }
}

__global__ __launch_bounds__(256) void gru_mv2(
    const float* __restrict__ Wi, const float* __restrict__ bi,
    const float* __restrict__ xcat2, const float* __restrict__ H,
    const float* __restrict__ G,
    float* __restrict__ out, float* __restrict__ hcat)
{
    const int row  = blockIdx.x * 4 + (threadIdx.x >> 6);
    const int lane = threadIdx.x & 63;

    const float4* __restrict__ W4 = (const float4*)(Wi + (size_t)row * KCAT);
    const float4* __restrict__ c0 = (const float4*)(xcat2);
    const float4* __restrict__ c1 = (const float4*)(xcat2 + KCAT);

    float s0 = 0.f, s1 = 0.f;
#pragma unroll 8
    for (int i = 0; i < KCAT / 4 / 64; ++i) {
        int idx = lane + i * 64;
        float4 w = W4[idx];
        float4 a = c0[idx], b = c1[idx];
        s0 += w.x * a.x + w.y * a.y + w.z * a.z + w.w * a.w;
        s1 += w.x * b.x + w.y * b.y + w.z * b.z + w.w * b.w;
    }
    s0 = wave_reduce64(s0);
    s1 = wave_reduce64(s1);
    if (lane == 0) {
        float bb  = bi[row];
        float hh0 = tanhf(s0 + bb);
        float hh1 = tanhf(s1 + bb);
        float g0  = G[row], g1 = G[NH + row];
        float hf  = g0 * H[row]      + (1.f - g0) * hh0;
        float hb  = g1 * H[NH + row] + (1.f - g1) * hh1;
        out[NH + row]     = hf;
        out[2 * NH + row] = hb;
        hcat[row]      = hf;
        hcat[NH + row] = hb;
    }
}

__global__ __launch_bounds__(256) void h2o_mv(
    const float* __restrict__ W, const float* __restrict__ b,
    const float* __restrict__ hcat, float* __restrict__ out)
{
    const int row  = blockIdx.x * 4 + (threadIdx.x >> 6);
    const int lane = threadIdx.x & 63;

    const float4* __restrict__ W4 = (const float4*)(W + (size_t)row * KCAT);
    const float4* __restrict__ x4 = (const float4*)(hcat);

    float s = 0.f;
#pragma unroll 8
    for (int i = 0; i < KCAT / 4 / 64; ++i) {
        int idx = lane + i * 64;
        float4 w = W4[idx];
        float4 a = x4[idx];
        s += w.x * a.x + w.y * a.y + w.z * a.z + w.w * a.w;
    }
    s = wave_reduce64(s);
    if (lane == 0)
        out[row] = s + b[row];
}

// ---------------------------------------------------------------------------
extern "C" void kernel_launch(void* const* d_in, const int* in_sizes, int n_in,
                              void* d_out, int out_size, void* d_ws, size_t ws_size,
                              hipStream_t stream) {
    const float* x_f   = (const float*)d_in[0];
    const float* x_b   = (const float*)d_in[1];
    const float* h_f   = (const float*)d_in[2];
    const float* h_b   = (const float*)d_in[3];
    const float* t_f   = (const float*)d_in[4];
    const float* t_b   = (const float*)d_in[5];
    const float* i2h_W = (const float*)d_in[6];
    const float* i2h_b = (const float*)d_in[7];
    const float* h2o_W = (const float*)d_in[8];
    const float* h2o_b = (const float*)d_in[9];
    const float* f_W1  = (const float*)d_in[10];
    const float* f_b1  = (const float*)d_in[11];
    const float* f_W2  = (const float*)d_in[12];
    const float* f_b2  = (const float*)d_in[13];
    float* out = (float*)d_out;

    // ---- workspace layout ----
    float* ws    = (float*)d_ws;
    float* bufA  = ws;                  // 2*NH
    float* bufB  = bufA  + 2 * NH;      // 2*NH
    float* V     = bufB  + 2 * NH;      // 2*NH
    float* Kv    = V     + 2 * NH;      // 2*NH
    float* xcat1 = Kv    + 2 * NH;      // 2*KCAT
    float* xcat2 = xcat1 + 2 * KCAT;    // 2*KCAT
    float* G     = xcat2 + 2 * KCAT;    // 2*NH
    float* hcat  = G     + 2 * NH;      // KCAT
    float* fend  = hcat  + KCAT;
    size_t fp32_bytes = (size_t)(fend - ws) * sizeof(float);   // ~328 KB, 16B-aligned
    ushort_t* W1b = (ushort_t*)((char*)d_ws + fp32_bytes);
    ushort_t* W2b = W1b + (size_t)NH * NH;
    size_t need_bf16 = fp32_bytes + 2 * (size_t)NH * NH * sizeof(ushort_t);  // ~67.4 MB
    const bool use_bf16 = ws_size >= need_bf16;

    dim3 blk(256);
    const int mv_grid = NH / 4;   // wave-per-row, 4 waves per block

    if (use_bf16) {
        const int n8 = NH * NH / 8;
        cvt_bf16_kernel<<<n8 / 256, blk, 0, stream>>>(f_W1, W1b, n8);
        cvt_bf16_kernel<<<n8 / 256, blk, 0, stream>>>(f_W2, W2b, n8);
    }

    init_h_kernel<<<NH / 256, blk, 0, stream>>>(h_f, h_b, bufA);

    float* H   = bufA;
    float* ACC = bufB;
    for (int s = 0; s < TPTS - 1; ++s) {
        if (use_bf16) {
            rk4_mv1_bf16<<<mv_grid, blk, 0, stream>>>(W1b, f_b1, H, Kv, t_f, t_b, s, 0.0f, 0, V);
            rk4_mv2_bf16<<<mv_grid, blk, 0, stream>>>(W2b, f_b2, V, t_f, t_b, s, 1.0f, H,   Kv, ACC);
            rk4_mv1_bf16<<<mv_grid, blk, 0, stream>>>(W1b, f_b1, H, Kv, t_f, t_b, s, 0.5f, 1, V);
            rk4_mv2_bf16<<<mv_grid, blk, 0, stream>>>(W2b, f_b2, V, t_f, t_b, s, 2.0f, ACC, Kv, ACC);
            rk4_mv1_bf16<<<mv_grid, blk, 0, stream>>>(W1b, f_b1, H, Kv, t_f, t_b, s, 0.5f, 1, V);
            rk4_mv2_bf16<<<mv_grid, blk, 0, stream>>>(W2b, f_b2, V, t_f, t_b, s, 2.0f, ACC, Kv, ACC);
            rk4_mv1_bf16<<<mv_grid, blk, 0, stream>>>(W1b, f_b1, H, Kv, t_f, t_b, s, 1.0f, 1, V);
            rk4_mv2_bf16<<<mv_grid, blk, 0, stream>>>(W2b, f_b2, V, t_f, t_b, s, 1.0f, ACC, Kv, ACC);
        } else {
            rk4_mv1_f32<<<mv_grid, blk, 0, stream>>>(f_W1, f_b1, H, Kv, t_f, t_b, s, 0.0f, 0, V);
            rk4_mv2_f32<<<mv_grid, blk, 0, stream>>>(f_W2, f_b2, V, t_f, t_b, s, 1.0f, H,   Kv, ACC);
            rk4_mv1_f32<<<mv_grid, blk, 0, stream>>>(f_W1, f_b1, H, Kv, t_f, t_b, s, 0.5f, 1, V);
            rk4_mv2_f32<<<mv_grid, blk, 0, stream>>>(f_W2, f_b2, V, t_f, t_b, s, 2.0f, ACC, Kv, ACC);
            rk4_mv1_f32<<<mv_grid, blk, 0, stream>>>(f_W1, f_b1, H, Kv, t_f, t_b, s, 0.5f, 1, V);
            rk4_mv2_f32<<<mv_grid, blk, 0, stream>>>(f_W2, f_b2, V, t_f, t_b, s, 2.0f, ACC, Kv, ACC);
            rk4_mv1_f32<<<mv_grid, blk, 0, stream>>>(f_W1, f_b1, H, Kv, t_f, t_b, s, 1.0f, 1, V);
            rk4_mv2_f32<<<mv_grid, blk, 0, stream>>>(f_W2, f_b2, V, t_f, t_b, s, 1.0f, ACC, Kv, ACC);
        }
        float* tmp = H; H = ACC; ACC = tmp;
    }

    build_xcat_kernel<<<NH / 256, blk, 0, stream>>>(x_f, x_b, H, xcat1, xcat2);
    gru_mv1<<<mv_grid, blk, 0, stream>>>(i2h_W, i2h_b, xcat1, H, G, xcat2);
    gru_mv2<<<mv_grid, blk, 0, stream>>>(i2h_W, i2h_b, xcat2, H, G, out, hcat);
    h2o_mv <<<mv_grid, blk, 0, stream>>>(h2o_W, h2o_b, hcat, out);
}